// Round 6
// baseline (343.661 us; speedup 1.0000x reference)
//
#include <hip/hip_runtime.h>
#include <math.h>

#define Tt 4096
#define Cc 1024
#define Hh 64

typedef __attribute__((ext_vector_type(8))) short bf16x8;
typedef __attribute__((ext_vector_type(4))) float f32x4;
typedef unsigned int u32;

__device__ inline unsigned short f2bf(float f) {
    unsigned u = __float_as_uint(f);
    u = (u + 0x7FFFu + ((u >> 16) & 1u)) >> 16;   // RNE
    return (unsigned short)u;
}

__device__ inline u32 pk2bf(float a, float b) {
#if __has_builtin(__builtin_amdgcn_cvt_pk_bf16_f32)
    typedef __attribute__((ext_vector_type(2))) __bf16 bf16x2_t;
    bf16x2_t v = __builtin_amdgcn_cvt_pk_bf16_f32(a, b);
    return __builtin_bit_cast(u32, v);
#else
    return (u32)f2bf(a) | ((u32)f2bf(b) << 16);
#endif
}

__device__ inline bf16x8 pack8(float4 lo, float4 hi) {
    union { u32 u[4]; bf16x8 v; } r;
    r.u[0] = pk2bf(lo.x, lo.y); r.u[1] = pk2bf(lo.z, lo.w);
    r.u[2] = pk2bf(hi.x, hi.y); r.u[3] = pk2bf(hi.z, hi.w);
    return r.v;
}

// async global->LDS 16B; lds base wave-uniform (HW: base + lane*16); global addr per-lane
__device__ inline void gl_lds16(const unsigned short* g, unsigned short* l) {
    __builtin_amdgcn_global_load_lds(
        (const __attribute__((address_space(1))) u32*)g,
        (__attribute__((address_space(3))) u32*)l, 16, 0, 0);
}

// ---------- W^T bf16 [192][1024] (kScale folded into Wq) + zero combine-flags ----------
__global__ __launch_bounds__(256) void wt_build(
    const float* __restrict__ Wq, const float* __restrict__ Wk,
    const float* __restrict__ Wv, unsigned short* __restrict__ Wt,
    int* __restrict__ flags)
{
    if (blockIdx.x == 0) { flags[threadIdx.x] = 0; flags[256 + threadIdx.x] = 0; }
    int e = blockIdx.x * 256 + threadIdx.x;   // 0..196607
    int k = e & 1023, n = e >> 10;
    float v;
    if (n < 64)       v = Wq[k * 64 + n] * 0.03125f;   // fold 1024^-0.5 into Q
    else if (n < 128) v = Wk[k * 64 + (n - 64)];
    else              v = Wv[k * 64 + (n - 128)];
    Wt[n * 1024 + k] = f2bf(v);
}

// ---------- QKV GEMM: barrier-free; wave-private frag-ordered B via gl_lds; A direct fp32 ----------
// 512 blocks x 4 waves; tile 32M x 192N; BK=32. Wave w owns n-tiles 3w..3w+2.
__global__ __launch_bounds__(256) void qkv_gemm(
    const float* __restrict__ x, const unsigned short* __restrict__ wt,
    unsigned short* __restrict__ qb, unsigned short* __restrict__ kb,
    unsigned short* __restrict__ vt)
{
    __shared__ unsigned short bs[4 * 2 * 3 * 512];   // 24576 B

    const int t = threadIdx.x, w = t >> 6, lane = t & 63;
    const int col = lane & 15, quad = lane >> 4;
    const int rowbase = (int)blockIdx.x * 32;

    const float* a0p = x + (long)(rowbase + col) * Cc + quad * 8;        // mt=0 row
    const float* a1p = x + (long)(rowbase + 16 + col) * Cc + quad * 8;   // mt=1 row
    const unsigned short* wb = wt + ((3 * w) * 16 + col) * Cc + quad * 8;
    unsigned short* bsw = bs + (w * 2) * 3 * 512;    // wave-private region

    f32x4 acc[2][3];
#pragma unroll
    for (int mt = 0; mt < 2; ++mt)
#pragma unroll
        for (int nt = 0; nt < 3; ++nt) acc[mt][nt] = (f32x4){0.f, 0.f, 0.f, 0.f};

    // prologue: stage step 0
#pragma unroll
    for (int nt = 0; nt < 3; ++nt)
        gl_lds16(wb + nt * 16 * Cc, bsw + nt * 512);
    float4 ar0 = *(const float4*)a0p, ar1 = *(const float4*)(a0p + 4);
    float4 ar2 = *(const float4*)a1p, ar3 = *(const float4*)(a1p + 4);

#pragma unroll 2
    for (int s = 0; s < 32; ++s) {
        const int cur = s & 1, nxt = cur ^ 1;
        const int kk = (s + 1) * 32;
        float4 an0, an1, an2, an3;
        if (s < 31) {
#pragma unroll
            for (int nt = 0; nt < 3; ++nt)
                gl_lds16(wb + nt * 16 * Cc + kk, bsw + (nxt * 3 + nt) * 512);
            an0 = *(const float4*)(a0p + kk); an1 = *(const float4*)(a0p + kk + 4);
            an2 = *(const float4*)(a1p + kk); an3 = *(const float4*)(a1p + kk + 4);
        }
        bf16x8 af0 = pack8(ar0, ar1);
        bf16x8 af1 = pack8(ar2, ar3);
#pragma unroll
        for (int nt = 0; nt < 3; ++nt) {
            bf16x8 bfr = *(const bf16x8*)&bsw[(cur * 3 + nt) * 512 + lane * 8];
            acc[0][nt] = __builtin_amdgcn_mfma_f32_16x16x32_bf16(af0, bfr, acc[0][nt], 0, 0, 0);
            acc[1][nt] = __builtin_amdgcn_mfma_f32_16x16x32_bf16(af1, bfr, acc[1][nt], 0, 0, 0);
        }
        if (s < 31) { ar0 = an0; ar1 = an1; ar2 = an2; ar3 = an3; }
    }

    // epilogue: C layout col=lane&15, row=quad*4+reg
    const long b = rowbase >> 12;
    const int tloc0 = (rowbase & 4095) + quad * 4;
#pragma unroll
    for (int mt = 0; mt < 2; ++mt)
#pragma unroll
        for (int nt = 0; nt < 3; ++nt) {
            int ng = 3 * w + nt, n = ng * 16 + col;
            int row = rowbase + mt * 16 + quad * 4;
            if (ng < 4) {
#pragma unroll
                for (int reg = 0; reg < 4; ++reg)
                    qb[(long)(row + reg) * Hh + n] = f2bf(acc[mt][nt][reg]);
            } else if (ng < 8) {
#pragma unroll
                for (int reg = 0; reg < 4; ++reg)
                    kb[(long)(row + reg) * Hh + (n - 64)] = f2bf(acc[mt][nt][reg]);
            } else {
                int h = n - 128;
                ushort4 pk = { f2bf(acc[mt][nt][0]), f2bf(acc[mt][nt][1]),
                               f2bf(acc[mt][nt][2]), f2bf(acc[mt][nt][3]) };
                *(ushort4*)&vt[b * Hh * Tt + (long)h * Tt + tloc0 + mt * 16] = pk;
            }
        }
}

// ---------- flash attention + fused combine ----------
// 1024 blocks = 512 tiles x 2 key-halves, LPT order. Static-max softmax, barrier-free K-loop.
// LDS: pl unioned with o_red (epilogue-only) -> 35 KB. NO min-waves launch bound:
// (256,4) capped VGPR at 64 -> K-loop spilled to scratch -> 4x regression (round 5).
#define LDP 56
#define LDO 68

__global__ __launch_bounds__(256) void attn(
    const unsigned short* __restrict__ qg, const unsigned short* __restrict__ kg,
    const unsigned short* __restrict__ vtg,
    float* __restrict__ po, float* __restrict__ pls,
    int* __restrict__ flags, float* __restrict__ out)
{
    __shared__ __align__(16) char smem[35344];
    float* o_red       = (float*)smem;                      // [128][68] f32 = 34816 B (epilogue)
    unsigned short* pl = (unsigned short*)smem;             // [4][32][56] bf16 = 14336 B (loop)
    float* lred        = (float*)(smem + 34816);            // 512 B
    int* lastf         = (int*)(smem + 35328);

    const int p    = blockIdx.x;
    const int qt   = 127 - (p >> 3);
    const int b    = p & 3;
    const int half = (p >> 2) & 1;
    const int tid  = (b << 7) | qt;
    const long qrow0 = (long)b * Tt + qt * 32;
    const int nkt = qt + 1;
    const int n0  = (nkt + 1) >> 1;
    const int cnt = half ? (nkt - n0) : n0;
    const int ust = half ? n0 : 0;

    const int t = threadIdx.x, w = t >> 6, lane = t & 63;
    const int col = lane & 15, quad = lane >> 4;
    const int plbase = w * 32 * LDP;

    bf16x8 qf[2][2];
#pragma unroll
    for (int mt = 0; mt < 2; ++mt)
#pragma unroll
        for (int kc = 0; kc < 2; ++kc)
            qf[mt][kc] = *(const bf16x8*)&qg[(qrow0 + mt * 16 + col) * Hh + kc * 32 + quad * 8];

    f32x4 oacc[2][4];
#pragma unroll
    for (int mt = 0; mt < 2; ++mt)
#pragma unroll
        for (int nt = 0; nt < 4; ++nt) oacc[mt][nt] = (f32x4){0.f, 0.f, 0.f, 0.f};
    float lsum[2][4] = {{0.f,0.f,0.f,0.f},{0.f,0.f,0.f,0.f}};

    for (int iu = w; iu < cnt; iu += 4) {
        const int u = ust + iu;
        const long krow0 = (long)b * Tt + u * 32;
        bf16x8 kf[2][2];
#pragma unroll
        for (int nt = 0; nt < 2; ++nt)
#pragma unroll
            for (int kc = 0; kc < 2; ++kc)
                kf[nt][kc] = *(const bf16x8*)&kg[(krow0 + nt * 16 + col) * Hh + kc * 32 + quad * 8];
        f32x4 s[2][2];
#pragma unroll
        for (int mt = 0; mt < 2; ++mt)
#pragma unroll
            for (int nt = 0; nt < 2; ++nt) {
                s[mt][nt] = (f32x4){0.f, 0.f, 0.f, 0.f};
#pragma unroll
                for (int kc = 0; kc < 2; ++kc)
                    s[mt][nt] = __builtin_amdgcn_mfma_f32_16x16x32_bf16(qf[mt][kc], kf[nt][kc], s[mt][nt], 0, 0, 0);
            }
#pragma unroll
        for (int mt = 0; mt < 2; ++mt)
#pragma unroll
            for (int reg = 0; reg < 4; ++reg) {
                int rloc = mt * 16 + quad * 4 + reg;
                if (u == qt) {                       // diagonal: mask key_local > row_local
                    if (col > rloc)      s[mt][0][reg] = -INFINITY;
                    if (16 + col > rloc) s[mt][1][reg] = -INFINITY;
                }
                float p0 = __expf(s[mt][0][reg]);
                float p1 = __expf(s[mt][1][reg]);
                lsum[mt][reg] += p0 + p1;
                pl[plbase + rloc * LDP + col]      = f2bf(p0);
                pl[plbase + rloc * LDP + 16 + col] = f2bf(p1);
            }
        bf16x8 af0 = *(const bf16x8*)&pl[plbase + col * LDP + quad * 8];
        bf16x8 af1 = *(const bf16x8*)&pl[plbase + (16 + col) * LDP + quad * 8];
#pragma unroll
        for (int nt = 0; nt < 4; ++nt) {
            bf16x8 vf = *(const bf16x8*)&vtg[((long)b * Hh + nt * 16 + col) * Tt + u * 32 + quad * 8];
            oacc[0][nt] = __builtin_amdgcn_mfma_f32_16x16x32_bf16(af0, vf, oacc[0][nt], 0, 0, 0);
            oacc[1][nt] = __builtin_amdgcn_mfma_f32_16x16x32_bf16(af1, vf, oacc[1][nt], 0, 0, 0);
        }
    }

    __syncthreads();   // all waves done with pl before o_red overwrites it
#pragma unroll
    for (int mt = 0; mt < 2; ++mt)
#pragma unroll
        for (int reg = 0; reg < 4; ++reg) {
            float l = lsum[mt][reg];
            l += __shfl_xor(l, 1); l += __shfl_xor(l, 2);
            l += __shfl_xor(l, 4); l += __shfl_xor(l, 8);
            if (col == 0) lred[w * 32 + mt * 16 + quad * 4 + reg] = l;
        }
#pragma unroll
    for (int mt = 0; mt < 2; ++mt)
#pragma unroll
        for (int nt = 0; nt < 4; ++nt)
#pragma unroll
            for (int reg = 0; reg < 4; ++reg)
                o_red[(w * 32 + mt * 16 + quad * 4 + reg) * LDO + nt * 16 + col] = oacc[mt][nt][reg];
    __syncthreads();
    if (t < 32)
        pls[(tid * 2 + half) * 32 + t] = lred[t] + lred[32 + t] + lred[64 + t] + lred[96 + t];
    float* pob = po + ((long)tid * 2 + half) * 2048;
#pragma unroll
    for (int j = 0; j < 8; ++j) {
        int e = t + 256 * j, r = e >> 6, c = e & 63;
        pob[e] = o_red[r * LDO + c] + o_red[(32 + r) * LDO + c]
               + o_red[(64 + r) * LDO + c] + o_red[(96 + r) * LDO + c];
    }

    // ---- fused combine: last block of this tile merges halves
    __threadfence();
    if (t == 0) *lastf = (atomicAdd(&flags[tid], 1) == 1);
    __syncthreads();
    if (*lastf) {
        __threadfence();
        const float* p0 = po + (long)tid * 2 * 2048;
        const float* p1 = p0 + 2048;
        const float* l0 = pls + tid * 64;
        const float* l1 = l0 + 32;
        float* op = out + qrow0 * Hh;
#pragma unroll
        for (int j = 0; j < 8; ++j) {
            int e = t + 256 * j, r = e >> 6;
            op[e] = (p0[e] + p1[e]) / (l0[r] + l1[r]);
        }
    }
}

extern "C" void kernel_launch(void* const* d_in, const int* in_sizes, int n_in,
                              void* d_out, int out_size, void* d_ws, size_t ws_size,
                              hipStream_t stream)
{
    const float* x  = (const float*)d_in[0];
    const float* Wq = (const float*)d_in[1];
    const float* Wk = (const float*)d_in[2];
    const float* Wv = (const float*)d_in[3];
    float* outp = (float*)d_out;

    unsigned short* wt = (unsigned short*)d_ws;       // 192*1024 bf16 (384 KB)
    unsigned short* qb = wt + 196608;                 // 2 MB
    unsigned short* kb = qb + 1048576;                // 2 MB
    unsigned short* vt = kb + 1048576;                // V^T [b][h][t] (2 MB)
    float* po   = (float*)(vt + 1048576);             // [512][2][2048] (8 MB)
    float* pls  = po + 2097152;                       // [512][2][32]
    int* flags  = (int*)(pls + 32768);                // [512]

    wt_build<<<dim3(768), dim3(256), 0, stream>>>(Wq, Wk, Wv, wt, flags);
    qkv_gemm<<<dim3(512), dim3(256), 0, stream>>>(x, wt, qb, kb, vt);
    attn<<<dim3(1024), dim3(256), 0, stream>>>(qb, kb, vt, po, pls, flags, outp);
}

// Round 7
// 180.859 us; speedup vs baseline: 1.9002x; 1.9002x over previous
//
#include <hip/hip_runtime.h>
#include <math.h>

#define Tt 4096
#define Cc 1024
#define Hh 64

typedef __attribute__((ext_vector_type(8))) short bf16x8;
typedef __attribute__((ext_vector_type(4))) float f32x4;
typedef unsigned int u32;

__device__ inline unsigned short f2bf(float f) {
    unsigned u = __float_as_uint(f);
    u = (u + 0x7FFFu + ((u >> 16) & 1u)) >> 16;   // RNE
    return (unsigned short)u;
}

__device__ inline u32 pk2bf(float a, float b) {
#if __has_builtin(__builtin_amdgcn_cvt_pk_bf16_f32)
    typedef __attribute__((ext_vector_type(2))) __bf16 bf16x2_t;
    bf16x2_t v = __builtin_amdgcn_cvt_pk_bf16_f32(a, b);
    return __builtin_bit_cast(u32, v);
#else
    return (u32)f2bf(a) | ((u32)f2bf(b) << 16);
#endif
}

__device__ inline bf16x8 pack8(float4 lo, float4 hi) {
    union { u32 u[4]; bf16x8 v; } r;
    r.u[0] = pk2bf(lo.x, lo.y); r.u[1] = pk2bf(lo.z, lo.w);
    r.u[2] = pk2bf(hi.x, hi.y); r.u[3] = pk2bf(hi.z, hi.w);
    return r.v;
}

// async global->LDS 16B; lds base wave-uniform (HW: base + lane*16); global addr per-lane
__device__ inline void gl_lds16(const unsigned short* g, unsigned short* l) {
    __builtin_amdgcn_global_load_lds(
        (const __attribute__((address_space(1))) u32*)g,
        (__attribute__((address_space(3))) u32*)l, 16, 0, 0);
}

// ---------- W^T bf16 [192][1024] (kScale folded into Wq) ----------
__global__ __launch_bounds__(256) void wt_build(
    const float* __restrict__ Wq, const float* __restrict__ Wk,
    const float* __restrict__ Wv, unsigned short* __restrict__ Wt)
{
    int e = blockIdx.x * 256 + threadIdx.x;   // 0..196607
    int k = e & 1023, n = e >> 10;
    float v;
    if (n < 64)       v = Wq[k * 64 + n] * 0.03125f;   // fold 1024^-0.5 into Q
    else if (n < 128) v = Wk[k * 64 + (n - 64)];
    else              v = Wv[k * 64 + (n - 128)];
    Wt[n * 1024 + k] = f2bf(v);
}

// ---------- QKV GEMM: barrier-free; wave-private frag-ordered B via gl_lds; A direct fp32 ----------
// 512 blocks x 4 waves; tile 32M x 192N; BK=32. Wave w owns n-tiles 3w..3w+2.
__global__ __launch_bounds__(256) void qkv_gemm(
    const float* __restrict__ x, const unsigned short* __restrict__ wt,
    unsigned short* __restrict__ qb, unsigned short* __restrict__ kb,
    unsigned short* __restrict__ vt)
{
    __shared__ unsigned short bs[4 * 2 * 3 * 512];   // 24576 B

    const int t = threadIdx.x, w = t >> 6, lane = t & 63;
    const int col = lane & 15, quad = lane >> 4;
    const int rowbase = (int)blockIdx.x * 32;

    const float* a0p = x + (long)(rowbase + col) * Cc + quad * 8;        // mt=0 row
    const float* a1p = x + (long)(rowbase + 16 + col) * Cc + quad * 8;   // mt=1 row
    const unsigned short* wb = wt + ((3 * w) * 16 + col) * Cc + quad * 8;
    unsigned short* bsw = bs + (w * 2) * 3 * 512;    // wave-private region

    f32x4 acc[2][3];
#pragma unroll
    for (int mt = 0; mt < 2; ++mt)
#pragma unroll
        for (int nt = 0; nt < 3; ++nt) acc[mt][nt] = (f32x4){0.f, 0.f, 0.f, 0.f};

    // prologue: stage step 0
#pragma unroll
    for (int nt = 0; nt < 3; ++nt)
        gl_lds16(wb + nt * 16 * Cc, bsw + nt * 512);
    float4 ar0 = *(const float4*)a0p, ar1 = *(const float4*)(a0p + 4);
    float4 ar2 = *(const float4*)a1p, ar3 = *(const float4*)(a1p + 4);

#pragma unroll 2
    for (int s = 0; s < 32; ++s) {
        const int cur = s & 1, nxt = cur ^ 1;
        const int kk = (s + 1) * 32;
        float4 an0, an1, an2, an3;
        if (s < 31) {
#pragma unroll
            for (int nt = 0; nt < 3; ++nt)
                gl_lds16(wb + nt * 16 * Cc + kk, bsw + (nxt * 3 + nt) * 512);
            an0 = *(const float4*)(a0p + kk); an1 = *(const float4*)(a0p + kk + 4);
            an2 = *(const float4*)(a1p + kk); an3 = *(const float4*)(a1p + kk + 4);
        }
        bf16x8 af0 = pack8(ar0, ar1);
        bf16x8 af1 = pack8(ar2, ar3);
#pragma unroll
        for (int nt = 0; nt < 3; ++nt) {
            bf16x8 bfr = *(const bf16x8*)&bsw[(cur * 3 + nt) * 512 + lane * 8];
            acc[0][nt] = __builtin_amdgcn_mfma_f32_16x16x32_bf16(af0, bfr, acc[0][nt], 0, 0, 0);
            acc[1][nt] = __builtin_amdgcn_mfma_f32_16x16x32_bf16(af1, bfr, acc[1][nt], 0, 0, 0);
        }
        if (s < 31) { ar0 = an0; ar1 = an1; ar2 = an2; ar3 = an3; }
    }

    // epilogue: C layout col=lane&15, row=quad*4+reg
    const long b = rowbase >> 12;
    const int tloc0 = (rowbase & 4095) + quad * 4;
#pragma unroll
    for (int mt = 0; mt < 2; ++mt)
#pragma unroll
        for (int nt = 0; nt < 3; ++nt) {
            int ng = 3 * w + nt, n = ng * 16 + col;
            int row = rowbase + mt * 16 + quad * 4;
            if (ng < 4) {
#pragma unroll
                for (int reg = 0; reg < 4; ++reg)
                    qb[(long)(row + reg) * Hh + n] = f2bf(acc[mt][nt][reg]);
            } else if (ng < 8) {
#pragma unroll
                for (int reg = 0; reg < 4; ++reg)
                    kb[(long)(row + reg) * Hh + (n - 64)] = f2bf(acc[mt][nt][reg]);
            } else {
                int h = n - 128;
                ushort4 pk = { f2bf(acc[mt][nt][0]), f2bf(acc[mt][nt][1]),
                               f2bf(acc[mt][nt][2]), f2bf(acc[mt][nt][3]) };
                *(ushort4*)&vt[b * Hh * Tt + (long)h * Tt + tloc0 + mt * 16] = pk;
            }
        }
}

// ---------- flash attention (round-4 proven config) ----------
// 1024 blocks = 512 tiles x 2 key-halves, LPT order. Static-max softmax, barrier-free K-loop.
// pl in its OWN LDS region (total 49.7 KB -> compiler targets 3 blocks/CU -> ~168 VGPR budget
// -> no in-loop spills). DO NOT shrink LDS below ~41 KB: round 5/6 showed the 4-blocks/CU
// target caps VGPR at 128 < ~140 live -> scratch spills in K-loop -> 4x regression.
#define LDP 56
#define LDO 68

__global__ __launch_bounds__(256) void attn(
    const unsigned short* __restrict__ qg, const unsigned short* __restrict__ kg,
    const unsigned short* __restrict__ vtg,
    float* __restrict__ po, float* __restrict__ pls)
{
    __shared__ __align__(16) char smem[49664];
    float* o_red       = (float*)smem;                      // 34816 B
    float* lred        = (float*)(smem + 34816);            // 512 B
    unsigned short* pl = (unsigned short*)(smem + 35328);   // 14336 B

    const int p    = blockIdx.x;
    const int qt   = 127 - (p >> 3);
    const int b    = p & 3;
    const int half = (p >> 2) & 1;
    const int tid  = (b << 7) | qt;
    const long qrow0 = (long)b * Tt + qt * 32;
    const int nkt = qt + 1;
    const int n0  = (nkt + 1) >> 1;
    const int cnt = half ? (nkt - n0) : n0;
    const int ust = half ? n0 : 0;

    const int t = threadIdx.x, w = t >> 6, lane = t & 63;
    const int col = lane & 15, quad = lane >> 4;
    const int plbase = w * 32 * LDP;

    bf16x8 qf[2][2];
#pragma unroll
    for (int mt = 0; mt < 2; ++mt)
#pragma unroll
        for (int kc = 0; kc < 2; ++kc)
            qf[mt][kc] = *(const bf16x8*)&qg[(qrow0 + mt * 16 + col) * Hh + kc * 32 + quad * 8];

    f32x4 oacc[2][4];
#pragma unroll
    for (int mt = 0; mt < 2; ++mt)
#pragma unroll
        for (int nt = 0; nt < 4; ++nt) oacc[mt][nt] = (f32x4){0.f, 0.f, 0.f, 0.f};
    float lsum[2][4] = {{0.f,0.f,0.f,0.f},{0.f,0.f,0.f,0.f}};

    for (int iu = w; iu < cnt; iu += 4) {
        const int u = ust + iu;
        const long krow0 = (long)b * Tt + u * 32;
        bf16x8 kf[2][2];
#pragma unroll
        for (int nt = 0; nt < 2; ++nt)
#pragma unroll
            for (int kc = 0; kc < 2; ++kc)
                kf[nt][kc] = *(const bf16x8*)&kg[(krow0 + nt * 16 + col) * Hh + kc * 32 + quad * 8];
        f32x4 s[2][2];
#pragma unroll
        for (int mt = 0; mt < 2; ++mt)
#pragma unroll
            for (int nt = 0; nt < 2; ++nt) {
                s[mt][nt] = (f32x4){0.f, 0.f, 0.f, 0.f};
#pragma unroll
                for (int kc = 0; kc < 2; ++kc)
                    s[mt][nt] = __builtin_amdgcn_mfma_f32_16x16x32_bf16(qf[mt][kc], kf[nt][kc], s[mt][nt], 0, 0, 0);
            }
#pragma unroll
        for (int mt = 0; mt < 2; ++mt)
#pragma unroll
            for (int reg = 0; reg < 4; ++reg) {
                int rloc = mt * 16 + quad * 4 + reg;
                if (u == qt) {                       // diagonal: mask key_local > row_local
                    if (col > rloc)      s[mt][0][reg] = -INFINITY;
                    if (16 + col > rloc) s[mt][1][reg] = -INFINITY;
                }
                float p0 = __expf(s[mt][0][reg]);
                float p1 = __expf(s[mt][1][reg]);
                lsum[mt][reg] += p0 + p1;
                pl[plbase + rloc * LDP + col]      = f2bf(p0);
                pl[plbase + rloc * LDP + 16 + col] = f2bf(p1);
            }
        bf16x8 af0 = *(const bf16x8*)&pl[plbase + col * LDP + quad * 8];
        bf16x8 af1 = *(const bf16x8*)&pl[plbase + (16 + col) * LDP + quad * 8];
#pragma unroll
        for (int nt = 0; nt < 4; ++nt) {
            bf16x8 vf = *(const bf16x8*)&vtg[((long)b * Hh + nt * 16 + col) * Tt + u * 32 + quad * 8];
            oacc[0][nt] = __builtin_amdgcn_mfma_f32_16x16x32_bf16(af0, vf, oacc[0][nt], 0, 0, 0);
            oacc[1][nt] = __builtin_amdgcn_mfma_f32_16x16x32_bf16(af1, vf, oacc[1][nt], 0, 0, 0);
        }
    }

#pragma unroll
    for (int mt = 0; mt < 2; ++mt)
#pragma unroll
        for (int reg = 0; reg < 4; ++reg) {
            float l = lsum[mt][reg];
            l += __shfl_xor(l, 1); l += __shfl_xor(l, 2);
            l += __shfl_xor(l, 4); l += __shfl_xor(l, 8);
            if (col == 0) lred[w * 32 + mt * 16 + quad * 4 + reg] = l;
        }
#pragma unroll
    for (int mt = 0; mt < 2; ++mt)
#pragma unroll
        for (int nt = 0; nt < 4; ++nt)
#pragma unroll
            for (int reg = 0; reg < 4; ++reg)
                o_red[(w * 32 + mt * 16 + quad * 4 + reg) * LDO + nt * 16 + col] = oacc[mt][nt][reg];
    __syncthreads();
    if (t < 32)
        pls[(tid * 2 + half) * 32 + t] = lred[t] + lred[32 + t] + lred[64 + t] + lred[96 + t];
    float* pob = po + ((long)tid * 2 + half) * 2048;
#pragma unroll
    for (int j = 0; j < 8; ++j) {
        int e = t + 256 * j, r = e >> 6, c = e & 63;
        pob[e] = o_red[r * LDO + c] + o_red[(32 + r) * LDO + c]
               + o_red[(64 + r) * LDO + c] + o_red[(96 + r) * LDO + c];
    }
}

// ---------- combine: out = (O0+O1)/(l0+l1) ----------
__global__ __launch_bounds__(256) void combine(
    const float* __restrict__ po, const float* __restrict__ pls, float* __restrict__ out)
{
    const int g = blockIdx.x;
    const long orow = (((long)(g >> 7)) * Tt + (long)(g & 127) * 32) * Hh;
    const float* p0 = po + (long)g * 2 * 2048;
    const float* p1 = p0 + 2048;
    const float* l0 = pls + g * 2 * 32;
    const float* l1 = l0 + 32;
    const int t = threadIdx.x;
#pragma unroll
    for (int j = 0; j < 8; ++j) {
        int e = t + 256 * j, r = e >> 6;
        out[orow + e] = (p0[e] + p1[e]) / (l0[r] + l1[r]);
    }
}

extern "C" void kernel_launch(void* const* d_in, const int* in_sizes, int n_in,
                              void* d_out, int out_size, void* d_ws, size_t ws_size,
                              hipStream_t stream)
{
    const float* x  = (const float*)d_in[0];
    const float* Wq = (const float*)d_in[1];
    const float* Wk = (const float*)d_in[2];
    const float* Wv = (const float*)d_in[3];
    float* outp = (float*)d_out;

    unsigned short* wt = (unsigned short*)d_ws;       // 192*1024 bf16 (384 KB)
    unsigned short* qb = wt + 196608;                 // 2 MB
    unsigned short* kb = qb + 1048576;                // 2 MB
    unsigned short* vt = kb + 1048576;                // V^T [b][h][t] (2 MB)
    float* po   = (float*)(vt + 1048576);             // [512][2][2048] (8 MB)
    float* pls  = po + 2097152;                       // [512][2][32]

    wt_build<<<dim3(768), dim3(256), 0, stream>>>(Wq, Wk, Wv, wt);
    qkv_gemm<<<dim3(512), dim3(256), 0, stream>>>(x, wt, qb, kb, vt);
    attn<<<dim3(1024), dim3(256), 0, stream>>>(qb, kb, vt, po, pls);
    combine<<<dim3(512), dim3(256), 0, stream>>>(po, pls, outp);
}